// Round 10
// baseline (366.692 us; speedup 1.0000x reference)
//
#include <hip/hip_runtime.h>
#include <hip/hip_fp16.h>
#include <stdint.h>

// ---------------------------------------------------------------------------
// Problem geometry (all compile-time):
//   x: (64, 48, 512, 2, 2) fp32. seq[s,n,f] = x[n, f>>2, 8*s, (f>>1)&1, f&1]
//   (only batch rows n<64 of the 512 matter downstream).
//   Layer1 BiGRU: in=192, H=256, 64 steps. Layer2 BiGRU: in=512, H=256.
//   Only final hiddens of layer2 used. dec_h = w_adj @ [hf,hb] + b_adj.
//   Decoder GRU (in=56, H=256) 6 steps, out = w_fc1@h + b_fc1 -> (64,6,56).
//
// RESIDENCY LEDGER (r2-r9, the whole saga):
//   r2: 768thr/128w-dwords, restrict -> compiler REMATERIALIZED loads in-loop
//       (VGPR=84), streamed from L2, ~50us/scan.
//   r3: 256thr/384w -> allocator allocated 256 then scratch-spilled the rest.
//   r4: (512,2) cap 128 -> spill. r5: AGPR asm parking -> spilled around asm.
//   r6/r7/r9: hybrid/resident attempts -> remat again (VGPR 116-128), 92us,
//       L2-BW-bound at 393KB/step/block ~= 1.28us/step.
// => r10 fix: make remat ILLEGAL. Weight ptr loses __restrict__; the step
//    loop contains an unconditional uint32_t store (packed y1) of the SAME
//    TBAA type as the weight loads -> may-alias -> loads cannot be sunk
//    into the loop -> must stay in registers. Demand ~150 < cap 170
//    (768thr, 3 waves/SIMD) -> no scratch pressure either.
// ---------------------------------------------------------------------------

#define HD 256
#define G3 768
#define NSEQ 64
#define NSTEP 64

typedef _Float16 hvec2 __attribute__((ext_vector_type(2)));
typedef _Float16 f16x8 __attribute__((ext_vector_type(8)));
typedef float f32x4 __attribute__((ext_vector_type(4)));

__device__ __forceinline__ float sigmf(float x) {
    return 1.0f / (1.0f + __expf(-x));
}

#if __has_builtin(__builtin_amdgcn_fdot2)
__device__ __forceinline__ float fdot2u(uint32_t w, uint32_t h, float acc) {
    return __builtin_amdgcn_fdot2(__builtin_bit_cast(hvec2, w),
                                  __builtin_bit_cast(hvec2, h), acc, false);
}
#else
__device__ __forceinline__ float fdot2u(uint32_t w, uint32_t h, float acc) {
    const __half2 wv = __builtin_bit_cast(__half2, w);
    const __half2 hv = __builtin_bit_cast(__half2, h);
    acc += __half2float(wv.x) * __half2float(hv.x);
    acc += __half2float(wv.y) * __half2float(hv.y);
    return acc;
}
#endif

__device__ __forceinline__ uint32_t pkh(float a, float b) {
    uint32_t lo = __half_as_ushort(__float2half_rn(a));
    uint32_t hi = __half_as_ushort(__float2half_rn(b));
    return lo | (hi << 16);
}

#define L32(X) X(0) X(1) X(2) X(3) X(4) X(5) X(6) X(7) \
  X(8) X(9) X(10) X(11) X(12) X(13) X(14) X(15) \
  X(16) X(17) X(18) X(19) X(20) X(21) X(22) X(23) \
  X(24) X(25) X(26) X(27) X(28) X(29) X(30) X(31)

// per-thread gate row j = threadIdx.x, full K: 32 uint4 = 128 weight dwords
#define LWG(i) const uint4 w##i = wq[(i) * G3];
#define DWG(i) { const uint4 hp = *(const uint4*)&hb[4 * (i)]; \
    a0 = fdot2u(w##i.x, hp.x, a0); a1 = fdot2u(w##i.y, hp.y, a1); \
    a2 = fdot2u(w##i.z, hp.z, a2); a3 = fdot2u(w##i.w, hp.w, a3); }

// ---------------- weight prep ----------------
// Repack Whh (768x256 fp32) -> uint4[q*768 + j], q=0..31: k=8q..8q+7 of row j.
__global__ __launch_bounds__(256) void pack_whhT(
    const float* __restrict__ w0, const float* __restrict__ w1,
    const float* __restrict__ w2, const float* __restrict__ w3,
    const float* __restrict__ w4,
    uint32_t* __restrict__ o0, uint32_t* __restrict__ o1,
    uint32_t* __restrict__ o2, uint32_t* __restrict__ o3,
    uint32_t* __restrict__ o4)
{
    const float* w; uint32_t* o;
    switch (blockIdx.y) {
        case 0: w = w0; o = o0; break;
        case 1: w = w1; o = o1; break;
        case 2: w = w2; o = o2; break;
        case 3: w = w3; o = o3; break;
        default: w = w4; o = o4; break;
    }
    int idx = blockIdx.x * 256 + threadIdx.x;    // 24576 total
    int j = idx >> 5, q = idx & 31;
    const float4 fa = *(const float4*)(w + j * HD + 8 * q);
    const float4 fb = *(const float4*)(w + j * HD + 8 * q + 4);
    uint4 r;
    r.x = pkh(fa.x, fa.y);
    r.y = pkh(fa.z, fa.w);
    r.z = pkh(fb.x, fb.y);
    r.w = pkh(fb.z, fb.w);
    ((uint4*)o)[q * G3 + j] = r;
}

// Wih fp32 -> f16 (same row-major layout), 4 tensors
__global__ __launch_bounds__(256) void pack_wih(
    const float* __restrict__ s0, const float* __restrict__ s1,
    const float* __restrict__ s2, const float* __restrict__ s3,
    __half* __restrict__ d0, __half* __restrict__ d1,
    __half* __restrict__ d2, __half* __restrict__ d3)
{
    const float* s; __half* d; int sz;
    switch (blockIdx.y) {
        case 0: s = s0; d = d0; sz = 147456; break;
        case 1: s = s1; d = d1; sz = 147456; break;
        case 2: s = s2; d = d2; sz = 393216; break;
        default: s = s3; d = d3; sz = 393216; break;
    }
    int i4 = blockIdx.x * 256 + threadIdx.x;
    if (i4 * 4 >= sz) return;
    const float4 v = *(const float4*)(s + i4 * 4);
    __half2 lo; lo.x = __float2half_rn(v.x); lo.y = __float2half_rn(v.y);
    __half2 hi; hi.x = __float2half_rn(v.z); hi.y = __float2half_rn(v.w);
    *(__half2*)(d + i4 * 4)     = lo;
    *(__half2*)(d + i4 * 4 + 2) = hi;
}

// fp32 transposes for decoder-input / adj / fc1 paths
__global__ __launch_bounds__(256) void prep_small(
    const float* __restrict__ wihd,   // (768,56)
    const float* __restrict__ wadj,   // (256,512)
    const float* __restrict__ wfc1,   // (56,256)
    float* __restrict__ wihdT,        // [v][j] 56x768
    float* __restrict__ wadjT,        // [f][i] 512x256
    float* __restrict__ wfc1T)        // [k][v] 256x56
{
    int idx = blockIdx.x * 256 + threadIdx.x;    // 188416 total
    if (idx < 43008) {
        int v = idx / G3, j = idx % G3;
        wihdT[idx] = wihd[j * 56 + v];
    } else if (idx < 43008 + 131072) {
        int i2 = idx - 43008;
        int f = i2 / HD, i = i2 % HD;
        wadjT[i2] = wadj[i * 512 + f];
    } else {
        int i3 = idx - 174080;
        int k = i3 / 56, v = i3 % 56;
        wfc1T[i3] = wfc1[v * HD + k];
    }
}

// gather seq rows (f16 out): seqg[(n*64+s)*192+f] = x[n, f>>2, 8s, (f>>1)&1, f&1]
__global__ __launch_bounds__(256) void gather_seq(
    const float* __restrict__ x, __half* __restrict__ seqg)
{
    int idx = blockIdx.x * 256 + threadIdx.x;    // 786432 total
    int f = idx % 192;
    int m = idx / 192;
    int n = m >> 6, s = m & 63;
    seqg[idx] = __float2half(x[n * 98304 + (f >> 2) * 2048 + s * 32 + (f & 3)]);
}

// ---------------- f16 MFMA GEMM with bias ----------------
// C[m][j] = sum_k A[m][k]*B[j][k] + bias[j]; M=4096, N=768, K in {192,512}.
// grid=(64, 12, 2); block = 4 waves; wave w computes rows m0+16w..+16,
// cols n0..n0+63 as 4 accumulators. No LDS: operands are L2-resident.
// C/D layout (HW-verified): col=lane&15, row=(lane>>4)*4+reg.
__global__ __launch_bounds__(256) void gemm_mfma(
    const __half* __restrict__ A,
    const __half* __restrict__ B0, const __half* __restrict__ B1,
    const float* __restrict__ bias0, const float* __restrict__ bias1,
    float* __restrict__ C0, float* __restrict__ C1, int K)
{
    const __half* B    = blockIdx.z ? B1 : B0;
    const float*  bias = blockIdx.z ? bias1 : bias0;
    float*        C    = blockIdx.z ? C1 : C0;
    const int m0 = blockIdx.x * 64;
    const int n0 = blockIdx.y * 64;
    const int w  = threadIdx.x >> 6;
    const int l  = threadIdx.x & 63;
    const int lr = l & 15;
    const int lk = (l >> 4) * 8;

    const __half* arow = A + (size_t)(m0 + w * 16 + lr) * K + lk;
    const __half* brow = B + (size_t)(n0 + lr) * K + lk;

    f32x4 acc0 = {0.f, 0.f, 0.f, 0.f};
    f32x4 acc1 = acc0, acc2 = acc0, acc3 = acc0;

#pragma unroll 2
    for (int k0 = 0; k0 < K; k0 += 32) {
        const f16x8 a  = *(const f16x8*)(arow + k0);
        const f16x8 b0 = *(const f16x8*)(brow + k0);
        const f16x8 b1 = *(const f16x8*)(brow + 16 * K + k0);
        const f16x8 b2 = *(const f16x8*)(brow + 32 * K + k0);
        const f16x8 b3 = *(const f16x8*)(brow + 48 * K + k0);
        acc0 = __builtin_amdgcn_mfma_f32_16x16x32_f16(a, b0, acc0, 0, 0, 0);
        acc1 = __builtin_amdgcn_mfma_f32_16x16x32_f16(a, b1, acc1, 0, 0, 0);
        acc2 = __builtin_amdgcn_mfma_f32_16x16x32_f16(a, b2, acc2, 0, 0, 0);
        acc3 = __builtin_amdgcn_mfma_f32_16x16x32_f16(a, b3, acc3, 0, 0, 0);
    }

    const int crow = m0 + w * 16 + (l >> 4) * 4;
    const int ccol = n0 + lr;
    float* cp = C + (size_t)crow * G3 + ccol;
    const float bb0 = bias[ccol];
    const float bb1 = bias[ccol + 16];
    const float bb2 = bias[ccol + 32];
    const float bb3 = bias[ccol + 48];
#pragma unroll
    for (int j = 0; j < 4; ++j) {
        cp[(size_t)j * G3 +  0] = acc0[j] + bb0;
        cp[(size_t)j * G3 + 16] = acc1[j] + bb1;
        cp[(size_t)j * G3 + 32] = acc2[j] + bb2;
        cp[(size_t)j * G3 + 48] = acc3[j] + bb3;
    }
}

// ---------------- register-resident GRU scan (768 thr, remat-proof) --------
// grid = 128 blocks: dir = blockIdx.x&1, n = blockIdx.x>>1.
// Thread j owns gate row j, full K: 32 uint4 = 128 weight VGPRs.
// wT is NOT __restrict__ and the loop stores uint32_t (packed y1) every
// step -> same-TBAA may-alias store -> weight loads cannot be sunk/remat'd.
// h double-buffered f16x2 in LDS; gi per-thread prefetch; 2 barriers/step.
__global__ __launch_bounds__(768, 3) void gru_scan(
    const float* giF, const float* giB,
    const uint32_t* wTF, const uint32_t* wTB,
    const float* __restrict__ bhhF, const float* __restrict__ bhhB,
    uint32_t* y1u, float* hfin)
{
    const int dir = blockIdx.x & 1;
    const int n   = blockIdx.x >> 1;
    const int t   = threadIdx.x;
    const float* gi  = dir ? giB : giF;
    const float* bhh = dir ? bhhB : bhhF;
    const uint4* wq  = (const uint4*)(dir ? wTB : wTF) + t;

    __shared__ __align__(16) uint32_t h1u[2][HD / 2];  // h as f16x2, dbuf
    __shared__ float s_rz[2 * HD];                     // gi+gh for r,z rows
    __shared__ float s_ghn[HD], s_inn[HD];             // n-row: gh, gi apart

    L32(LWG)
    const float bh = bhh[t];

    float h_own = 0.0f;
    if (t < HD / 2) h1u[0][t] = 0u;
    __syncthreads();

    const float* gbase = gi + (size_t)n * NSTEP * G3;
    int s = dir ? (NSTEP - 1) : 0;
    float g_own = gbase[s * G3 + t];

    for (int step = 0; step < NSTEP; ++step) {
        const int s_nxt = dir ? (step < NSTEP - 1 ? NSTEP - 2 - step : 0)
                              : (step < NSTEP - 1 ? step + 1 : NSTEP - 1);
        const float g_nxt = gbase[s_nxt * G3 + t];   // hidden under matvec

        const uint32_t* hb = h1u[step & 1];
        float a0 = 0.f, a1 = 0.f, a2 = 0.f, a3 = 0.f;
        L32(DWG)
        const float acc = bh + ((a0 + a1) + (a2 + a3));

        if (t < 2 * HD) {
            s_rz[t] = g_own + acc;
        } else {
            s_ghn[t - 2 * HD] = acc;
            s_inn[t - 2 * HD] = g_own;
        }
        __syncthreads();
        if (t < HD) {
            const float r  = sigmf(s_rz[t]);
            const float z  = sigmf(s_rz[HD + t]);
            const float nn = tanhf(s_inn[t] + r * s_ghn[t]);
            const float hnew = (1.0f - z) * nn + z * h_own;
            h_own = hnew;
            ((__half*)h1u[(step + 1) & 1])[t] = __float2half(hnew);
        }
        __syncthreads();
        // packed u32 y1 store: REQUIRED for the anti-remat alias barrier.
        if (t < HD / 2)
            y1u[(size_t)(n * NSTEP + s) * 256 + dir * 128 + t] =
                h1u[(step + 1) & 1][t];
        g_own = g_nxt;
        s = s_nxt;
    }
    if (t < HD)
        hfin[(size_t)(dir * NSEQ + n) * HD + t] = h_own;
}

// ---------------- dec_h = w_adj @ [hf,hb] + b_adj ----------------
__global__ __launch_bounds__(256) void adj_kernel(
    const float* __restrict__ hfin, const float* __restrict__ wadjT,
    const float* __restrict__ badj, float* __restrict__ dech)
{
    const int n = blockIdx.x, t = threadIdx.x;
    __shared__ float comb[512];
    comb[t]      = hfin[(size_t)n * HD + t];
    comb[HD + t] = hfin[(size_t)(NSEQ + n) * HD + t];
    __syncthreads();
    float acc = badj[t];
#pragma unroll 8
    for (int f = 0; f < 512; ++f) acc += wadjT[f * HD + t] * comb[f];
    dech[n * HD + t] = acc;
}

// ---------------- decoder: 64 blocks x 768 threads, streamed weights -------
__global__ __launch_bounds__(768, 3) void decoder_kernel(
    const float* __restrict__ dech, const uint32_t* __restrict__ wTd,
    const float* __restrict__ wihdT, const float* __restrict__ bihd,
    const float* __restrict__ bhhd, const float* __restrict__ wfc1T,
    const float* __restrict__ bfc1, float* __restrict__ out)
{
    const int n = blockIdx.x, t = threadIdx.x;
    const uint4* wq = (const uint4*)wTd + t;

    __shared__ __align__(16) uint32_t h1u[2][HD / 2];
    __shared__ float ghs[G3], gis[G3];
    __shared__ float hfp[HD];
    __shared__ float inp[56];
    __shared__ float pf1[448];

    const float bi = bihd[t], bh = bhhd[t];

    float h_own = 0.0f;
    if (t < HD) {
        const float hv = dech[(size_t)n * HD + t];
        h_own = hv;
        ((__half*)h1u[0])[t] = __float2half(hv);
        hfp[t] = hv;
    }
    if (t < 56) inp[t] = 0.0f;
    __syncthreads();

    for (int step = 0; step < 6; ++step) {
        const uint32_t* hb = h1u[step & 1];
        float a0 = 0.f, a1 = 0.f;
#pragma unroll 8
        for (int q = 0; q < 32; ++q) {
            const uint4 w = wq[q * G3];
            const uint4 hp = *(const uint4*)&hb[4 * q];
            a0 = fdot2u(w.x, hp.x, a0); a1 = fdot2u(w.y, hp.y, a1);
            a0 = fdot2u(w.z, hp.z, a0); a1 = fdot2u(w.w, hp.w, a1);
        }
        float ai = bi;
#pragma unroll 8
        for (int v = 0; v < 56; ++v) ai += wihdT[v * G3 + t] * inp[v];
        ghs[t] = a0 + a1 + bh;
        gis[t] = ai;
        __syncthreads();
        if (t < HD) {
            const float r  = sigmf(gis[t] + ghs[t]);
            const float z  = sigmf(gis[HD + t] + ghs[HD + t]);
            const float nn = tanhf(gis[2 * HD + t] + r * ghs[2 * HD + t]);
            const float hnew = (1.0f - z) * nn + z * h_own;
            h_own = hnew;
            ((__half*)h1u[(step + 1) & 1])[t] = __float2half(hnew);
            hfp[t] = hnew;
        }
        __syncthreads();
        if (t < 448) {
            const int v = t >> 3, g = t & 7;
            float o = 0.f;
#pragma unroll
            for (int k2 = 0; k2 < 32; ++k2)
                o += wfc1T[(g * 32 + k2) * 56 + v] * hfp[g * 32 + k2];
            pf1[t] = o;
        }
        __syncthreads();
        if (t < 56) {
            float o = bfc1[t];
#pragma unroll
            for (int g = 0; g < 8; ++g) o += pf1[t * 8 + g];
            out[(size_t)n * 336 + step * 56 + t] = o;
            inp[t] = o;
        }
        __syncthreads();
    }
}

// ---------------------------------------------------------------------------
extern "C" void kernel_launch(void* const* d_in, const int* in_sizes, int n_in,
                              void* d_out, int out_size, void* d_ws, size_t ws_size,
                              hipStream_t stream)
{
    const float* x      = (const float*)d_in[0];
    const float* wih1f  = (const float*)d_in[1];
    const float* whh1f  = (const float*)d_in[2];
    const float* bih1f  = (const float*)d_in[3];
    const float* bhh1f  = (const float*)d_in[4];
    const float* wih1b  = (const float*)d_in[5];
    const float* whh1b  = (const float*)d_in[6];
    const float* bih1b  = (const float*)d_in[7];
    const float* bhh1b  = (const float*)d_in[8];
    const float* wih2f  = (const float*)d_in[9];
    const float* whh2f  = (const float*)d_in[10];
    const float* bih2f  = (const float*)d_in[11];
    const float* bhh2f  = (const float*)d_in[12];
    const float* wih2b  = (const float*)d_in[13];
    const float* whh2b  = (const float*)d_in[14];
    const float* bih2b  = (const float*)d_in[15];
    const float* bhh2b  = (const float*)d_in[16];
    const float* wihd   = (const float*)d_in[17];
    const float* whhd   = (const float*)d_in[18];
    const float* bihd   = (const float*)d_in[19];
    const float* bhhd   = (const float*)d_in[20];
    const float* wfc1   = (const float*)d_in[21];
    const float* bfc1   = (const float*)d_in[22];
    const float* wadj   = (const float*)d_in[23];
    const float* badj   = (const float*)d_in[24];

    float* ws = (float*)d_ws;
    __half*   seqg_h  = (__half*)(ws + 0);           // 786432 f16
    float*    gi_f    = ws + 393216;                 // 3145728
    float*    gi_b    = ws + 3538944;                // 3145728
    uint32_t* y1u     = (uint32_t*)(ws + 6684672);   // 1048576 u32 (2M f16)
    float*    hfin    = ws + 7733248;                // 32768
    float*    dech    = ws + 7766016;                // 16384
    uint32_t* wt1f    = (uint32_t*)(ws + 7782400);   // 98304 each
    uint32_t* wt1b    = (uint32_t*)(ws + 7880704);
    uint32_t* wt2f    = (uint32_t*)(ws + 7979008);
    uint32_t* wt2b    = (uint32_t*)(ws + 8077312);
    uint32_t* wtd     = (uint32_t*)(ws + 8175616);
    __half*   wih1f_h = (__half*)(ws + 8273920);     // 147456 f16
    __half*   wih1b_h = (__half*)(ws + 8347648);
    __half*   wih2f_h = (__half*)(ws + 8421376);     // 393216 f16
    __half*   wih2b_h = (__half*)(ws + 8617984);
    float*    wihdT   = ws + 8814592;                // 43008
    float*    wadjT   = ws + 8857600;                // 131072
    float*    wfc1T   = ws + 8988672;                // 14336

    pack_whhT<<<dim3(96, 5), 256, 0, stream>>>(
        whh1f, whh1b, whh2f, whh2b, whhd, wt1f, wt1b, wt2f, wt2b, wtd);
    pack_wih<<<dim3(384, 4), 256, 0, stream>>>(
        wih1f, wih1b, wih2f, wih2b, wih1f_h, wih1b_h, wih2f_h, wih2b_h);
    prep_small<<<736, 256, 0, stream>>>(wihd, wadj, wfc1, wihdT, wadjT, wfc1T);
    gather_seq<<<3072, 256, 0, stream>>>(x, seqg_h);

    // layer 1
    gemm_mfma<<<dim3(64, 12, 2), 256, 0, stream>>>(
        seqg_h, wih1f_h, wih1b_h, bih1f, bih1b, gi_f, gi_b, 192);
    gru_scan<<<128, 768, 0, stream>>>(
        gi_f, gi_b, wt1f, wt1b, bhh1f, bhh1b, y1u, hfin);

    // layer 2 (gi buffers reused; y1u is dead storage during scan 2)
    gemm_mfma<<<dim3(64, 12, 2), 256, 0, stream>>>(
        (const __half*)y1u, wih2f_h, wih2b_h, bih2f, bih2b, gi_f, gi_b, 512);
    gru_scan<<<128, 768, 0, stream>>>(
        gi_f, gi_b, wt2f, wt2b, bhh2f, bhh2b, y1u, hfin);

    // decoder head
    adj_kernel<<<64, 256, 0, stream>>>(hfin, wadjT, badj, dech);
    decoder_kernel<<<64, 768, 0, stream>>>(
        dech, wtd, wihdT, bihd, bhhd, wfc1T, bfc1, (float*)d_out);
}